// Round 6
// baseline (302.006 us; speedup 1.0000x reference)
//
#include <hip/hip_runtime.h>
#include <math.h>

static constexpr int NB    = 4;
static constexpr int CDIM  = 256;
static constexpr int TOK   = 4096;
static constexpr int NHEAD = 4;
static constexpr int DHEAD = 64;
static constexpr int NT    = TOK / 64;   // 64 key-tiles of 64 keys

typedef short           bf16x8_t  __attribute__((ext_vector_type(8)));
typedef float           f32x4_t   __attribute__((ext_vector_type(4)));
typedef unsigned short  ushort8_t __attribute__((ext_vector_type(8)));
typedef unsigned int    uint4_t   __attribute__((ext_vector_type(4)));

__device__ __forceinline__ unsigned short f2bf_rne(float f) {
    unsigned x = __builtin_bit_cast(unsigned, f);
    x += 0x7fffu + ((x >> 16) & 1u);
    return (unsigned short)(x >> 16);
}
__device__ __forceinline__ float bf2f(unsigned short u) {
    return __builtin_bit_cast(float, (unsigned)u << 16);
}
__device__ __forceinline__ unsigned cvtpk(float lo, float hi) {
    unsigned r;
    asm("v_cvt_pk_bf16_f32 %0, %1, %2" : "=v"(r) : "v"(lo), "v"(hi));
    return r;
}

// ---------------------------------------------------------------------------
// Kernel 1: QKV projection (fp32 VALU GEMM). Epilogue emits bf16 hi/lo planes.
// mask * scale * log2(e) folded into q so attention softmax can use exp2.
// ---------------------------------------------------------------------------
__global__ __launch_bounds__(256)
void qkv_gemm(const float* __restrict__ x, const float* __restrict__ Wq,
              const float* __restrict__ bq, const float* __restrict__ mask,
              unsigned short* __restrict__ qhi, unsigned short* __restrict__ qlo,
              unsigned short* __restrict__ khi, unsigned short* __restrict__ klo,
              unsigned short* __restrict__ vthi, unsigned short* __restrict__ vtlo)
{
    const int col0 = blockIdx.x * 64;
    const int t0   = blockIdx.y * 64;
    const int n    = blockIdx.z;
    const int tid  = threadIdx.x;
    const int tx   = tid & 15, ty = tid >> 4;

    __shared__ float As[32][64];
    __shared__ float Bs[32][64];

    float acc[4][4] = {};
    const float* xn = x + (size_t)n * CDIM * TOK;

    for (int k0 = 0; k0 < CDIM; k0 += 32) {
        __syncthreads();
        #pragma unroll
        for (int i = 0; i < 2; ++i) {
            int idx = tid + i * 256;
            int cl = idx >> 4, q4 = idx & 15;
            *(float4*)&As[cl][q4 * 4] =
                *(const float4*)(xn + (size_t)(k0 + cl) * TOK + t0 + q4 * 4);
            *(float4*)&Bs[cl][q4 * 4] =
                *(const float4*)(Wq + (size_t)(k0 + cl) * 768 + col0 + q4 * 4);
        }
        __syncthreads();
        #pragma unroll
        for (int kk = 0; kk < 32; ++kk) {
            float4 a = *(const float4*)&As[kk][ty * 4];
            float4 b = *(const float4*)&Bs[kk][tx * 4];
            float ar[4] = {a.x, a.y, a.z, a.w};
            float br[4] = {b.x, b.y, b.z, b.w};
            #pragma unroll
            for (int r = 0; r < 4; ++r)
                #pragma unroll
                for (int c = 0; c < 4; ++c)
                    acc[r][c] += ar[r] * br[c];
        }
    }

    const int part = col0 >> 8;            // 0=q 1=k 2=v
    const int head = (col0 & 255) >> 6;
    const size_t hb = (size_t)(n * NHEAD + head) * TOK * DHEAD;
    float4 bias = *(const float4*)(bq + col0 + tx * 4);
    float bb[4] = {bias.x, bias.y, bias.z, bias.w};

    float vals[4][4];
    #pragma unroll
    for (int r = 0; r < 4; ++r)
        #pragma unroll
        for (int c = 0; c < 4; ++c)
            vals[r][c] = acc[r][c] + bb[c];

    if (part == 0) {
        #pragma unroll
        for (int r = 0; r < 4; ++r) {
            int t = t0 + ty * 4 + r;
            float mv = mask[(size_t)n * TOK + t] * 0.0625f * 1.4426950408889634f;
            #pragma unroll
            for (int c = 0; c < 4; ++c) vals[r][c] *= mv;
        }
    }

    if (part <= 1) {
        unsigned short* hp = (part == 0) ? qhi : khi;
        unsigned short* lp = (part == 0) ? qlo : klo;
        #pragma unroll
        for (int r = 0; r < 4; ++r) {
            int t = t0 + ty * 4 + r;
            ushort4 hh, ll;
            unsigned short* hc = (unsigned short*)&hh;
            unsigned short* lc = (unsigned short*)&ll;
            #pragma unroll
            for (int c = 0; c < 4; ++c) {
                hc[c] = f2bf_rne(vals[r][c]);
                lc[c] = f2bf_rne(vals[r][c] - bf2f(hc[c]));
            }
            *(ushort4*)&hp[hb + (size_t)t * DHEAD + tx * 4] = hh;
            *(ushort4*)&lp[hb + (size_t)t * DHEAD + tx * 4] = ll;
        }
    } else {
        #pragma unroll
        for (int c = 0; c < 4; ++c) {
            int d = tx * 4 + c;
            ushort4 hh, ll;
            unsigned short* hc = (unsigned short*)&hh;
            unsigned short* lc = (unsigned short*)&ll;
            #pragma unroll
            for (int r = 0; r < 4; ++r) {
                hc[r] = f2bf_rne(vals[r][c]);
                lc[r] = f2bf_rne(vals[r][c] - bf2f(hc[r]));
            }
            *(ushort4*)&vthi[hb + (size_t)d * TOK + t0 + ty * 4] = hh;
            *(ushort4*)&vtlo[hb + (size_t)d * TOK + t0 + ty * 4] = ll;
        }
    }
}

// ---------------------------------------------------------------------------
// Kernel 2: flash attention, swapped-QK MFMA, in-register P, QBLK=128.
//  - sa = mfma(K, Q): lane owns one q-row (q = w*16 + l15) -> lane-local softmax
//  - P redistributed to PV A-fragments with cvt_pk + 12 shfl_xor (no LDS P)
//  - PV = mfma(V, P): output col = q -> rescale/normalize stay lane-local
//  - 2 q-subtiles per wave (QBLK=128): K/V LDS reads amortized 2x
//  - 2 lgkm-only barriers per tile; register-staged K/V prefetch (T14)
// ---------------------------------------------------------------------------
#define MFMA(a, b, c) __builtin_amdgcn_mfma_f32_16x16x32_bf16((a), (b), (c), 0, 0, 0)
#define LGKM_BAR() asm volatile("s_waitcnt lgkmcnt(0)\n\ts_barrier" ::: "memory")

__global__ __launch_bounds__(256, 2)
void attn_mfma(const unsigned short* __restrict__ qhi, const unsigned short* __restrict__ qlo,
               const unsigned short* __restrict__ khi, const unsigned short* __restrict__ klo,
               const unsigned short* __restrict__ vthi, const unsigned short* __restrict__ vtlo,
               float* __restrict__ out)
{
    __shared__ __align__(16) unsigned char smem_raw[64 * 132 * 4];   // 33 KiB
    unsigned short* smem = (unsigned short*)smem_raw;
    constexpr int K_HI = 0, K_LO = 4096, V_HI = 8192, V_LO = 12288;  // ushort offs

    const int bid  = blockIdx.x;
    const int p    = (bid & 7) | (((bid >> 3) & 1) << 3);   // (n,head) 0..15
    const int tile = bid >> 4;                              // 0..31
    const int n = p >> 2, h = p & 3;
    const int t0 = tile * 128;

    const int tid  = threadIdx.x;
    const int lane = tid & 63, w = tid >> 6;
    const int l15  = lane & 15, g = lane >> 4;
    const int gr   = tid & 7, r2 = (tid >> 3) & 31;
    const int dst0 = r2 * 64 + ((gr ^ (r2 & 7)) << 3);

    const size_t base = (size_t)(n * NHEAD + h) * TOK * DHEAD;

    // ---- prologue: K/V(0) prefetch + Q fragments straight from global ----
    ushort8_t skh0, skh1, skl0, skl1, svh0, svh1, svl0, svl1;
    {
        size_t ks_ = base + (size_t)r2 * DHEAD + gr * 8;
        size_t vs_ = base + (size_t)r2 * TOK + gr * 8;
        skh0 = *(const ushort8_t*)&khi[ks_];
        skh1 = *(const ushort8_t*)&khi[ks_ + 32 * DHEAD];
        skl0 = *(const ushort8_t*)&klo[ks_];
        skl1 = *(const ushort8_t*)&klo[ks_ + 32 * DHEAD];
        svh0 = *(const ushort8_t*)&vthi[vs_];
        svh1 = *(const ushort8_t*)&vthi[vs_ + 32 * TOK];
        svl0 = *(const ushort8_t*)&vtlo[vs_];
        svl1 = *(const ushort8_t*)&vtlo[vs_ + 32 * TOK];
    }

    bf16x8_t qh[2][2], ql[2][2];
    #pragma unroll
    for (int u = 0; u < 2; ++u)
        #pragma unroll
        for (int ks = 0; ks < 2; ++ks) {
            size_t qa = base + (size_t)(t0 + u * 64 + w * 16 + l15) * DHEAD + ks * 32 + g * 8;
            qh[u][ks] = __builtin_bit_cast(bf16x8_t, *(const ushort8_t*)&qhi[qa]);
            ql[u][ks] = __builtin_bit_cast(bf16x8_t, *(const ushort8_t*)&qlo[qa]);
        }

    // stage K/V(0)
    *(ushort8_t*)&smem[K_HI + dst0]        = skh0;
    *(ushort8_t*)&smem[K_HI + dst0 + 2048] = skh1;
    *(ushort8_t*)&smem[K_LO + dst0]        = skl0;
    *(ushort8_t*)&smem[K_LO + dst0 + 2048] = skl1;
    *(ushort8_t*)&smem[V_HI + dst0]        = svh0;
    *(ushort8_t*)&smem[V_HI + dst0 + 2048] = svh1;
    *(ushort8_t*)&smem[V_LO + dst0]        = svl0;
    *(ushort8_t*)&smem[V_LO + dst0 + 2048] = svl1;

    float mreg[2] = {-1e30f, -1e30f}, lsum[2] = {0.f, 0.f};
    f32x4_t oa[2][4];
    #pragma unroll
    for (int u = 0; u < 2; ++u)
        #pragma unroll
        for (int db = 0; db < 4; ++db) oa[u][db] = (f32x4_t){0.f, 0.f, 0.f, 0.f};

    for (int kt = 0; kt < NT; ++kt) {
        LGKM_BAR();   // staged K/V(kt) visible (lgkm-only)

        // ---- prefetch K/V(kt+1) into regs (clamped on last iter) ----
        {
            int ktn = (kt + 1 < NT) ? kt + 1 : kt;
            size_t ks_ = base + (size_t)(ktn * 64 + r2) * DHEAD + gr * 8;
            size_t vs_ = base + (size_t)r2 * TOK + ktn * 64 + gr * 8;
            skh0 = *(const ushort8_t*)&khi[ks_];
            skh1 = *(const ushort8_t*)&khi[ks_ + 32 * DHEAD];
            skl0 = *(const ushort8_t*)&klo[ks_];
            skl1 = *(const ushort8_t*)&klo[ks_ + 32 * DHEAD];
            svh0 = *(const ushort8_t*)&vthi[vs_];
            svh1 = *(const ushort8_t*)&vthi[vs_ + 32 * TOK];
            svl0 = *(const ushort8_t*)&vtlo[vs_];
            svl1 = *(const ushort8_t*)&vtlo[vs_ + 32 * TOK];
        }

        // ---- S^T = K Q^T: sa[u][kb][r] = S[k = kb*16+g*4+r][q = u*64+w*16+l15]
        f32x4_t sa[2][4];
        #pragma unroll
        for (int u = 0; u < 2; ++u)
            #pragma unroll
            for (int kb = 0; kb < 4; ++kb) sa[u][kb] = (f32x4_t){0.f, 0.f, 0.f, 0.f};

        __builtin_amdgcn_s_setprio(1);
        #pragma unroll
        for (int ks = 0; ks < 2; ++ks) {
            #pragma unroll
            for (int kb = 0; kb < 4; ++kb) {
                int row = kb * 16 + l15;
                int idx = row * 64 + (((ks * 4 + g) ^ (row & 7)) << 3);
                bf16x8_t kh = __builtin_bit_cast(bf16x8_t, *(const ushort8_t*)&smem[K_HI + idx]);
                bf16x8_t kl = __builtin_bit_cast(bf16x8_t, *(const ushort8_t*)&smem[K_LO + idx]);
                sa[0][kb] = MFMA(kh, qh[0][ks], sa[0][kb]);
                sa[0][kb] = MFMA(kl, qh[0][ks], sa[0][kb]);
                sa[0][kb] = MFMA(kh, ql[0][ks], sa[0][kb]);
                sa[1][kb] = MFMA(kh, qh[1][ks], sa[1][kb]);
                sa[1][kb] = MFMA(kl, qh[1][ks], sa[1][kb]);
                sa[1][kb] = MFMA(kh, ql[1][ks], sa[1][kb]);
            }
        }
        __builtin_amdgcn_s_setprio(0);

        // ---- lane-local online softmax + in-register P redistribution ----
        bf16x8_t pa[2][2];
        #pragma unroll
        for (int u = 0; u < 2; ++u) {
            float mx = fmaxf(fmaxf(sa[u][0][0], sa[u][0][1]), fmaxf(sa[u][0][2], sa[u][0][3]));
            #pragma unroll
            for (int kb = 1; kb < 4; ++kb) {
                mx = fmaxf(mx, fmaxf(fmaxf(sa[u][kb][0], sa[u][kb][1]),
                                     fmaxf(sa[u][kb][2], sa[u][kb][3])));
            }
            mx = fmaxf(mx, __shfl_xor(mx, 16));
            mx = fmaxf(mx, __shfl_xor(mx, 32));
            if (!__all(mx <= mreg[u])) {          // exact deferred rescale
                float mn = fmaxf(mreg[u], mx);
                float al = __builtin_amdgcn_exp2f(mreg[u] - mn);
                mreg[u] = mn;
                lsum[u] *= al;
                #pragma unroll
                for (int db = 0; db < 4; ++db) {
                    oa[u][db][0] *= al; oa[u][db][1] *= al;
                    oa[u][db][2] *= al; oa[u][db][3] *= al;
                }
            }
            float pp[4][4];
            float rs = 0.f;
            #pragma unroll
            for (int kb = 0; kb < 4; ++kb)
                #pragma unroll
                for (int r = 0; r < 4; ++r) {
                    pp[kb][r] = __builtin_amdgcn_exp2f(sa[u][kb][r] - mreg[u]);
                    rs += pp[kb][r];
                }
            rs += __shfl_xor(rs, 16);
            rs += __shfl_xor(rs, 32);
            lsum[u] += rs;

            unsigned pk[4][2];
            #pragma unroll
            for (int kb = 0; kb < 4; ++kb) {
                pk[kb][0] = cvtpk(pp[kb][0], pp[kb][1]);
                pk[kb][1] = cvtpk(pp[kb][2], pp[kb][3]);
            }
            // redistribute: lane (q=l15, g') holds P[k=kb*16+g'*4+r][q];
            // PV A-frag needs lane (q=l15, g) octet: k = ks*32 + g*8 + j.
            #pragma unroll
            for (int ks = 0; ks < 2; ++ks) {
                unsigned a0, a1, a2, a3;
                #pragma unroll
                for (int hh = 0; hh < 2; ++hh) {
                    unsigned xa = (g & 1) ? pk[2 * ks][hh] : pk[2 * ks + 1][hh];
                    unsigned s16 = __shfl_xor((int)xa, 16);
                    unsigned s32 = __shfl_xor((int)xa, 32);
                    unsigned xb = (g & 1) ? pk[2 * ks + 1][hh] : pk[2 * ks][hh];
                    unsigned s48 = __shfl_xor((int)xb, 48);
                    unsigned alo = (g == 0) ? pk[2 * ks][hh]
                                 : (g == 1) ? s48
                                 : (g == 2) ? s32 : s16;
                    unsigned ahi = (g == 3) ? pk[2 * ks + 1][hh]
                                 : (g == 0) ? s16
                                 : (g == 1) ? s32 : s48;
                    if (hh == 0) { a0 = alo; a2 = ahi; }
                    else         { a1 = alo; a3 = ahi; }
                }
                uint4_t av = {a0, a1, a2, a3};
                pa[u][ks] = __builtin_bit_cast(bf16x8_t, av);
            }
        }

        // ---- O^acc += V^T P : oa[u][db] cols = q (lane-local) ----
        __builtin_amdgcn_s_setprio(1);
        #pragma unroll
        for (int ks = 0; ks < 2; ++ks) {
            #pragma unroll
            for (int db = 0; db < 4; ++db) {
                int vrow = db * 16 + l15;
                int vidx = vrow * 64 + (((ks * 4 + g) ^ (vrow & 7)) << 3);
                bf16x8_t vh = __builtin_bit_cast(bf16x8_t, *(const ushort8_t*)&smem[V_HI + vidx]);
                bf16x8_t vl = __builtin_bit_cast(bf16x8_t, *(const ushort8_t*)&smem[V_LO + vidx]);
                oa[0][db] = MFMA(vh, pa[0][ks], oa[0][db]);
                oa[0][db] = MFMA(vl, pa[0][ks], oa[0][db]);
                oa[1][db] = MFMA(vh, pa[1][ks], oa[1][db]);
                oa[1][db] = MFMA(vl, pa[1][ks], oa[1][db]);
            }
        }
        __builtin_amdgcn_s_setprio(0);

        LGKM_BAR();   // all reads of K/V(kt) complete

        if (kt + 1 < NT) {
            *(ushort8_t*)&smem[K_HI + dst0]        = skh0;
            *(ushort8_t*)&smem[K_HI + dst0 + 2048] = skh1;
            *(ushort8_t*)&smem[K_LO + dst0]        = skl0;
            *(ushort8_t*)&smem[K_LO + dst0 + 2048] = skl1;
            *(ushort8_t*)&smem[V_HI + dst0]        = svh0;
            *(ushort8_t*)&smem[V_HI + dst0 + 2048] = svh1;
            *(ushort8_t*)&smem[V_LO + dst0]        = svl0;
            *(ushort8_t*)&smem[V_LO + dst0 + 2048] = svl1;
        }
    }

    // ---- epilogue: normalize (lane-local), LDS transpose, coalesced store ----
    float* Os = (float*)smem_raw;   // [64 d][132 stride] floats
    #pragma unroll
    for (int u = 0; u < 2; ++u) {
        float rl = 1.0f / lsum[u];
        #pragma unroll
        for (int db = 0; db < 4; ++db)
            #pragma unroll
            for (int r = 0; r < 4; ++r)
                Os[(db * 16 + g * 4 + r) * 132 + u * 64 + w * 16 + l15] = oa[u][db][r] * rl;
    }
    LGKM_BAR();
    {
        int d = tid >> 2, qo = (tid & 3) * 32;
        float* og = out + ((size_t)n * CDIM + h * DHEAD + d) * TOK + t0 + qo;
        #pragma unroll
        for (int j = 0; j < 8; ++j)
            *(float4*)&og[j * 4] = *(const float4*)&Os[d * 132 + qo + j * 4];
    }
}

// ---------------------------------------------------------------------------
extern "C" void kernel_launch(void* const* d_in, const int* in_sizes, int n_in,
                              void* d_out, int out_size, void* d_ws, size_t ws_size,
                              hipStream_t stream)
{
    const float* x    = (const float*)d_in[0];
    const float* mask = (const float*)d_in[1];
    const float* Wq   = (const float*)d_in[2];
    const float* bq   = (const float*)d_in[3];
    float* out = (float*)d_out;

    const size_t PL = (size_t)NB * NHEAD * TOK * DHEAD;
    unsigned short* qhi  = (unsigned short*)d_ws;
    unsigned short* qlo  = qhi  + PL;
    unsigned short* khi  = qlo  + PL;
    unsigned short* klo  = khi  + PL;
    unsigned short* vthi = klo  + PL;
    unsigned short* vtlo = vthi + PL;

    qkv_gemm<<<dim3(12, 64, 4), 256, 0, stream>>>(x, Wq, bq, mask,
                                                  qhi, qlo, khi, klo, vthi, vtlo);
    attn_mfma<<<dim3(512), 256, 0, stream>>>(qhi, qlo, khi, klo, vthi, vtlo, out);
}